// Round 17
// baseline (5172.768 us; speedup 1.0000x reference)
//
#include <hip/hip_runtime.h>
#include <stdint.h>

// ---------------------------------------------------------------------------
// Seq2seq (2-layer LSTM encoder + attention decoder) on MI355X.
// Numerics: "ph2" split-fp16: value = hi(f16) + lo(f16) * 2^-11; GEMMs do 3
// MFMA products (hi*hi -> acc0, lo*hi + hi*lo -> acc1, result acc0+acc1/2048).
// Round 17: PRODUCER-CONSUMER WAVE SPECIALIZATION. k_lstm2 widened to 512
//   threads: waves 0-3 = REC ring (round-16 champion, unchanged); waves 4-7
//   compute NEXT chunk's Xg = Ap@Wih0^T GEMM in the ring's idle slack,
//   reading fl-layout frags straight from global (no LDS), 2x2 register
//   blocking, one K-slice per tick, fp16 out to ping-pong Xg. All barriers
//   outside the role branch -> counts match (3 + nt*4 for all waves).
//   3 serial GEMM0 dispatches deleted. Whh1 lo-plane dropped (-64 AGPR)
//   to fund GEMM accumulators (round-14 regalloc lesson).
// ---------------------------------------------------------------------------

typedef _Float16 f16;
typedef f16 f16x8 __attribute__((ext_vector_type(8)));
typedef float f32x4 __attribute__((ext_vector_type(4)));

#define LOSCALE 2048.0f
#define LOINV   (1.0f/2048.0f)

#define B_  128
#define S_  256
#define H_  512

__device__ __forceinline__ uint16_t hbits(f16 h){ union{ f16 f; uint16_t u; } c; c.f=h; return c.u; }
__device__ __forceinline__ float f16val(uint16_t u){ union{ uint16_t u; f16 f; } c; c.u=u; return (float)c.f; }

__device__ __forceinline__ uint32_t split_ph2(float x){
  f16 h = (f16)x;
  float r = (x - (float)h) * LOSCALE;
  return (uint32_t)hbits(h) | ((uint32_t)hbits((f16)r) << 16);
}
__device__ __forceinline__ float ph2val(uint32_t p){
  union{ uint16_t u; f16 f; } a, b; a.u = (uint16_t)p; b.u = (uint16_t)(p>>16);
  return (float)a.f + (float)b.f * LOINV;
}

__device__ __forceinline__ void pack_hi_lo(const uint4& a, const uint4& b, uint4& hi, uint4& lo){
  hi = make_uint4((a.x & 0xffffu) | (a.y << 16),
                  (a.z & 0xffffu) | (a.w << 16),
                  (b.x & 0xffffu) | (b.y << 16),
                  (b.z & 0xffffu) | (b.w << 16));
  lo = make_uint4((a.x >> 16) | (a.y & 0xffff0000u),
                  (a.z >> 16) | (a.w & 0xffff0000u),
                  (b.x >> 16) | (b.y & 0xffff0000u),
                  (b.z >> 16) | (b.w & 0xffff0000u));
}

__device__ __forceinline__ void split_pack8(const float* x, uint4& hi, uint4& lo){
  uint16_t h[8], l[8];
#pragma unroll
  for (int e = 0; e < 8; ++e) {
    f16 hh = (f16)x[e];
    float r = (x[e] - (float)hh) * LOSCALE;
    h[e] = hbits(hh); l[e] = hbits((f16)r);
  }
  hi = make_uint4((uint32_t)h[0]|((uint32_t)h[1]<<16), (uint32_t)h[2]|((uint32_t)h[3]<<16),
                  (uint32_t)h[4]|((uint32_t)h[5]<<16), (uint32_t)h[6]|((uint32_t)h[7]<<16));
  lo = make_uint4((uint32_t)l[0]|((uint32_t)l[1]<<16), (uint32_t)l[2]|((uint32_t)l[3]<<16),
                  (uint32_t)l[4]|((uint32_t)l[5]<<16), (uint32_t)l[6]|((uint32_t)l[7]<<16));
}

__device__ __forceinline__ f32x4 mfma16(uint4 a, uint4 b, f32x4 c){
  return __builtin_amdgcn_mfma_f32_16x16x32_f16(
      __builtin_bit_cast(f16x8, a), __builtin_bit_cast(f16x8, b), c, 0, 0, 0);
}

__device__ __forceinline__ float sigm(float x){ return 1.0f/(1.0f + expf(-x)); }
__device__ __forceinline__ float fsigm(float x){ return 1.0f/(1.0f + __expf(-x)); }
__device__ __forceinline__ float ftanh(float x){
  float ax = fabsf(x);
  float e = __expf(-2.0f*ax);
  float r = (1.0f - e)/(1.0f + e);
  return copysignf(r, x);
}

__device__ __forceinline__ uint32_t plane_word(uint32_t p, uint32_t pp, int odd){
  return odd ? ((pp >> 16) | (p & 0xffff0000u))
             : ((p & 0xffffu) | (pp << 16));
}

__device__ __forceinline__ size_t fl_idx(int row, int k){
  return (size_t)(k >> 5) * 4096 + (size_t)(row >> 4) * 512 + (size_t)(k & 1) * 256
       + (size_t)((k >> 3) & 3) * 64 + (size_t)(row & 15) * 4 + (size_t)((k & 7) >> 1);
}

__device__ __forceinline__ void gload_lds16(const uint32_t* gbase, uint32_t* lbase, int lane){
#if __has_builtin(__builtin_amdgcn_global_load_lds)
  __builtin_amdgcn_global_load_lds(
      (const __attribute__((address_space(1))) uint32_t*)(gbase + lane*4),
      (__attribute__((address_space(3))) uint32_t*)lbase, 16, 0, 0);
#else
  *(uint4*)(lbase + lane*4) = *(const uint4*)(gbase + lane*4);
#endif
}

// ---------------------------------------------------------------------------
// K1: embedding gather -> fl layout
// ---------------------------------------------------------------------------
__global__ __launch_bounds__(256) void k_embed_src_fl(const int* __restrict__ tok,
    const float* __restrict__ emb, uint32_t* __restrict__ out)
{
  const size_t total = (size_t)S_ * B_ * H_;
  for (size_t i = (size_t)blockIdx.x*256 + threadIdx.x; i < total; i += (size_t)gridDim.x*256) {
    int s = (int)(i >> 16), b = (int)((i >> 9) & 127), k = (int)(i & 511);
    int t = tok[b*S_ + s];
    uint32_t p = split_ph2(emb[(size_t)t*H_ + k]);
    uint32_t pp = __shfl_xor(p, 1);
    out[(size_t)s*65536 + fl_idx(b, k)] = plane_word(p, pp, k & 1);
  }
}

__global__ __launch_bounds__(256) void k_embed_trg(const int* __restrict__ tok,
    const float* __restrict__ emb, uint32_t* __restrict__ out)
{
  int i = blockIdx.x*256 + threadIdx.x;   // 65536
  int e = i & (H_-1), b = i >> 9;
  int t = tok[b];
  out[i] = split_ph2(emb[(size_t)t*H_ + e]);
}

// W f32 [N][512] -> fl ph2
__global__ __launch_bounds__(256) void k_packW(const float* __restrict__ W,
    uint32_t* __restrict__ out)
{
  int i = blockIdx.x*256 + threadIdx.x;
  int n = i >> 9, k = i & 511;
  uint32_t p = split_ph2(W[i]);
  uint32_t pp = __shfl_xor(p, 1);
  out[(size_t)(n >> 7)*65536 + fl_idx(n & 127, k)] = plane_word(p, pp, k & 1);
}

// a f32 -> linear ph2
__global__ __launch_bounds__(256) void k_pack1(const float* __restrict__ a,
    uint32_t* __restrict__ out)
{ int i = blockIdx.x*256 + threadIdx.x; out[i] = split_ph2(a[i]); }

// ---------------------------------------------------------------------------
// K2a: fl GEMM — staging via global_load_lds, zero repack VALU. K=512.
// outMode: 0 = f32 C, 2 = fp16 C (u16/elem; addC must be 0 for mode 2).
// ---------------------------------------------------------------------------
__global__ __launch_bounds__(256,2) void k_gemm_fl(
    const uint32_t* __restrict__ Afl,
    const uint32_t* __restrict__ Wfl,
    const float* __restrict__ b0, const float* __restrict__ b1,
    float* __restrict__ C, int N, int addC, int outMode)
{
  __shared__ uint8_t sm[65536];
  const int tid = threadIdx.x, lane = tid & 63, wv = tid >> 6;
  const int wm = wv >> 1, wn = wv & 1;
  const int bn0 = blockIdx.x * 128, bm0 = blockIdx.y * 128;
  const uint32_t* Ab = Afl + (size_t)blockIdx.y * 65536;
  const uint32_t* Wb = Wfl + (size_t)blockIdx.x * 65536;

  f32x4 acc0[4][4], acc1[4][4];
#pragma unroll
  for (int i = 0; i < 4; ++i)
#pragma unroll
    for (int j = 0; j < 4; ++j) { acc0[i][j] = (f32x4){0,0,0,0}; acc1[i][j] = (f32x4){0,0,0,0}; }

  for (int it = 0; it < 8; ++it) {
    __syncthreads();
    {
      const uint32_t* gsrc = (wv < 2 ? Ab : Wb) + (size_t)it*8192 + (size_t)(wv & 1)*4096;
      uint32_t* lb = (uint32_t*)(sm + (size_t)wv*16384);
#pragma unroll
      for (int e = 0; e < 16; ++e)
        gload_lds16(gsrc + e*256, lb + e*256, lane);
    }
    asm volatile("s_waitcnt vmcnt(0)" ::: "memory");
    __syncthreads();

#pragma unroll
    for (int kt = 0; kt < 2; ++kt) {
      uint4 ah[4], al[4];
#pragma unroll
      for (int i = 0; i < 4; ++i) {
        const uint8_t* p = sm + (size_t)(kt*8 + wm*4 + i)*2048 + lane*16;
        ah[i] = *(const uint4*)p; al[i] = *(const uint4*)(p + 1024);
      }
#pragma unroll
      for (int j = 0; j < 4; ++j) {
        const uint8_t* p = sm + 32768 + (size_t)(kt*8 + wn*4 + j)*2048 + lane*16;
        uint4 bh = *(const uint4*)p;
        uint4 bl = *(const uint4*)(p + 1024);
#pragma unroll
        for (int i = 0; i < 4; ++i) {
          acc0[i][j] = mfma16(ah[i], bh, acc0[i][j]);
          acc1[i][j] = mfma16(al[i], bh, acc1[i][j]);
          acc1[i][j] = mfma16(ah[i], bl, acc1[i][j]);
        }
      }
    }
  }

#pragma unroll
  for (int i = 0; i < 4; ++i) {
    int row0 = bm0 + (wm*4+i)*16 + ((lane>>4)<<2);
#pragma unroll
    for (int j = 0; j < 4; ++j) {
      int col = bn0 + (wn*4+j)*16 + (lane & 15);
      float bias = 0.f;
      if (b0) bias += b0[col];
      if (b1) bias += b1[col];
      f32x4 v = acc0[i][j] + acc1[i][j] * LOINV;
#pragma unroll
      for (int r = 0; r < 4; ++r) {
        size_t idx = (size_t)(row0 + r) * N + col;
        float out = v[r] + bias;
        if (addC) out += C[idx];
        if (outMode == 2) ((uint16_t*)C)[idx] = hbits((f16)out);
        else              C[idx] = out;
      }
    }
  }
}

// ---------------------------------------------------------------------------
// K2b: legacy GEMM (f32 weights, linear ph2 A) — decoder matmuls + logits
// ---------------------------------------------------------------------------
__global__ __launch_bounds__(256,2) void k_gemm(
    const uint32_t* __restrict__ A, int lda,
    const float* __restrict__ W, int ldw,
    const float* __restrict__ b0, const float* __restrict__ b1,
    float* __restrict__ C, int N, int K, int addC)
{
  __shared__ uint8_t sm[65536];
  const int tid = threadIdx.x;
  const int lane = tid & 63, wv = tid >> 6;
  const int wm = wv >> 1, wn = wv & 1;
  const int bn0 = blockIdx.x * 128, bm0 = blockIdx.y * 128;

  const int srow = tid >> 1;
  const int skh  = (tid & 1) * 32;
  const int smt  = srow >> 4, sr = srow & 15, skt = tid & 1;

  f32x4 acc0[4][4], acc1[4][4];
#pragma unroll
  for (int i = 0; i < 4; ++i)
#pragma unroll
    for (int j = 0; j < 4; ++j) { acc0[i][j] = (f32x4){0,0,0,0}; acc1[i][j] = (f32x4){0,0,0,0}; }

  for (int k0 = 0; k0 < K; k0 += 64) {
    __syncthreads();
    {
      const uint32_t* ap = A + (size_t)(bm0 + srow) * lda + (k0 + skh);
      uint4 q[8];
#pragma unroll
      for (int e = 0; e < 8; ++e) q[e] = *(const uint4*)(ap + e*4);
#pragma unroll
      for (int kg = 0; kg < 4; ++kg) {
        uint4 hi, lo; pack_hi_lo(q[2*kg], q[2*kg+1], hi, lo);
        uint8_t* dst = sm + (size_t)(smt*2 + skt)*2048 + (size_t)(sr + 16*kg)*16;
        *(uint4*)dst = hi; *(uint4*)(dst + 1024) = lo;
      }
    }
    {
      const float* wp = W + (size_t)(bn0 + srow) * ldw + (k0 + skh);
      float xs[32];
#pragma unroll
      for (int e = 0; e < 8; ++e) { float4 v = *(const float4*)(wp + e*4);
        xs[e*4+0]=v.x; xs[e*4+1]=v.y; xs[e*4+2]=v.z; xs[e*4+3]=v.w; }
#pragma unroll
      for (int kg = 0; kg < 4; ++kg) {
        uint4 hi, lo; split_pack8(xs + kg*8, hi, lo);
        uint8_t* dst = sm + 32768 + (size_t)(smt*2 + skt)*2048 + (size_t)(sr + 16*kg)*16;
        *(uint4*)dst = hi; *(uint4*)(dst + 1024) = lo;
      }
    }
    __syncthreads();

#pragma unroll
    for (int kt = 0; kt < 2; ++kt) {
      uint4 ah[4], al[4];
#pragma unroll
      for (int i = 0; i < 4; ++i) {
        const uint8_t* p = sm + (size_t)(((wm*4+i)*2 + kt))*2048 + lane*16;
        ah[i] = *(const uint4*)p; al[i] = *(const uint4*)(p + 1024);
      }
#pragma unroll
      for (int j = 0; j < 4; ++j) {
        const uint8_t* p = sm + 32768 + (size_t)(((wn*4+j)*2 + kt))*2048 + lane*16;
        uint4 bh = *(const uint4*)p;
        uint4 bl = *(const uint4*)(p + 1024);
#pragma unroll
        for (int i = 0; i < 4; ++i) {
          acc0[i][j] = mfma16(ah[i], bh, acc0[i][j]);
          acc1[i][j] = mfma16(al[i], bh, acc1[i][j]);
          acc1[i][j] = mfma16(ah[i], bl, acc1[i][j]);
        }
      }
    }
  }

#pragma unroll
  for (int i = 0; i < 4; ++i) {
    int row0 = bm0 + (wm*4+i)*16 + ((lane>>4)<<2);
#pragma unroll
    for (int j = 0; j < 4; ++j) {
      int col = bn0 + (wn*4+j)*16 + (lane & 15);
      float bias = 0.f;
      if (b0) bias += b0[col];
      if (b1) bias += b1[col];
      f32x4 v = acc0[i][j] + acc1[i][j] * LOINV;
#pragma unroll
      for (int r = 0; r < 4; ++r) {
        size_t idx = (size_t)(row0 + r) * N + col;
        float out = v[r] + bias;
        if (addC) out += C[idx];
        C[idx] = out;
      }
    }
  }
}

// ---------------------------------------------------------------------------
// K3: FUSED two-layer recurrence (waves 0-3) + next-chunk Xg GEMM (waves 4-7).
// 512 threads. Barriers all outside the role branch: 3 pre-loop + 4/tick.
// ---------------------------------------------------------------------------
__global__ __launch_bounds__(512,1) void k_lstm2(
    const float* __restrict__ Whh0, const float* __restrict__ Whh1,
    const float* __restrict__ bih1, const float* __restrict__ bhh1,
    const uint16_t* __restrict__ xg,      // [64][128][2048] fp16 (L0 chunk)
    const int*  __restrict__ lens,
    uint32_t* __restrict__ mb0,           // [2][8][8192] u32
    uint32_t* __restrict__ mb1,
    float* __restrict__ cb0, float* __restrict__ cb1,
    uint32_t* __restrict__ y1buf,         // fl [256][65536]
    uint32_t* __restrict__ flg0, uint32_t* __restrict__ flg1,   // [8][32]
    uint32_t* __restrict__ xcdclaim,      // [8] at stride 16 u32
    const uint32_t* __restrict__ Wp1,     // Wih1 fl [16][65536]
    const uint32_t* __restrict__ Wp0,     // Wih0 fl [16][65536]
    const uint32_t* __restrict__ ApN,     // next chunk embeds fl [64][65536]
    uint16_t* __restrict__ XgN,           // next chunk Xg fp16 out
    const float* __restrict__ bih0, const float* __restrict__ bhh0,
    int doGemm, int s0, int nt)
{
  __shared__ uint8_t sm[139264];
  uint8_t* wih   = sm;                      // 64KB Wih1 hi-plane frags
  uint8_t* tileA = sm + 65536;              // 32KB h0 tile
  uint8_t* tileB = sm + 98304;              // 32KB h1 tile
  uint64_t* tA64 = (uint64_t*)tileA;
  uint64_t* tB64 = (uint64_t*)tileB;
  float* g0ex = (float*)(sm + 131072);      // 4KB (dedicated)
  float* g1ex = (float*)(sm + 135168);      // 4KB (dedicated)

  const int tid = threadIdx.x, lane = tid & 63, wv = tid >> 6;
  const bool rec = (wv < 4);
  const int row = lane & 15, qh = lane >> 4;

  // ---- runtime role claim (REC only consumes it) ----
  uint32_t* claim_sh = (uint32_t*)tileA;
  if (tid == 0) {
    uint32_t xcd;
    asm volatile("s_getreg_b32 %0, hwreg(HW_REG_XCC_ID)" : "=s"(xcd));
    xcd &= 7u;
    uint32_t pos = __hip_atomic_fetch_add(xcdclaim + xcd*16, 1u,
                     __ATOMIC_RELAXED, __HIP_MEMORY_SCOPE_SYSTEM);
    claim_sh[0] = xcd | ((pos & 31u) << 8);
  }
  asm volatile("s_waitcnt lgkmcnt(0)" ::: "memory");
  __builtin_amdgcn_s_barrier();                        // pre-1
  int bg = 0, hs = 0;
  if (rec) {
    const uint32_t cl = claim_sh[0];
    bg = (int)(cl & 7u); hs = (int)((cl >> 8) & 31u);
  }
  __builtin_amdgcn_s_barrier();                        // pre-2

  // ---- REC setup: Wih1 hi-plane -> LDS, Whh0 (hi+lo) + Whh1 (hi) -> regs ----
  uint4 w0h[16], w0l[16], w1h[16];
  int b_l = 0, uu = 0, bglob = 0, len_b = 0, lenA = 0;
  size_t bgoff = 0, widx = 0, yfl = 0;
  float c0_reg = 0.f, c1_reg = 0.f, h0_reg = 0.f, h1_reg = 0.f;
  float b1g[4] = {0.f, 0.f, 0.f, 0.f};
  if (rec) {
    {
      const uint32_t* wpb = Wp1 + (size_t)(wv*4 + (hs >> 3))*65536 + (size_t)(hs & 7)*512;
      uint32_t* lb = (uint32_t*)(wih + (size_t)wv*16384);
#pragma unroll
      for (int kt = 0; kt < 16; ++kt)
        gload_lds16(wpb + kt*4096, lb + kt*256, lane);
    }
    {
      const float* r0 = Whh0 + (size_t)(wv*512 + hs*16 + row)*512 + qh*8;
      const float* r1 = Whh1 + (size_t)(wv*512 + hs*16 + row)*512 + qh*8;
#pragma unroll
      for (int kt = 0; kt < 16; ++kt) {
        float xs[8];
        float4 v0 = *(const float4*)(r0 + kt*32), v1 = *(const float4*)(r0 + kt*32 + 4);
        xs[0]=v0.x; xs[1]=v0.y; xs[2]=v0.z; xs[3]=v0.w;
        xs[4]=v1.x; xs[5]=v1.y; xs[6]=v1.z; xs[7]=v1.w;
        split_pack8(xs, w0h[kt], w0l[kt]);
        v0 = *(const float4*)(r1 + kt*32); v1 = *(const float4*)(r1 + kt*32 + 4);
        xs[0]=v0.x; xs[1]=v0.y; xs[2]=v0.z; xs[3]=v0.w;
        xs[4]=v1.x; xs[5]=v1.y; xs[6]=v1.z; xs[7]=v1.w;
        uint4 dummy;
        split_pack8(xs, w1h[kt], dummy);
        (void)dummy;
      }
    }
    b_l = tid >> 4; uu = tid & 15;
    bglob = bg*16 + b_l;
    bgoff = (size_t)bg*8192;
    const int oct_p = hs*2 + (uu >> 3);
    widx = (size_t)b_l*512 + (size_t)(uu & 1)*256
         + ((size_t)(oct_p ^ b_l) << 2) + (size_t)((uu & 7) >> 1);
    len_b = lens[bglob];
    lenA  = lens[bg*16 + row];
    c0_reg = cb0[(size_t)bglob*512 + hs*16 + uu];
    c1_reg = cb1[(size_t)bglob*512 + hs*16 + uu];
    {
      size_t ib = (size_t)(s0 & 1)*65536 + bgoff + (size_t)b_l*512
                + ((size_t)(oct_p ^ b_l) << 2) + (size_t)((uu & 7) >> 1);
      uint32_t hiw = mb0[ib], low = mb0[ib + 256];
      int sh = (uu & 1) * 16;
      h0_reg = f16val((uint16_t)(hiw >> sh)) + f16val((uint16_t)(low >> sh)) * LOINV;
      int s1i = (s0 >= 1) ? (s0 - 1) : 0;
      size_t ib1 = (size_t)(s1i & 1)*65536 + bgoff + (size_t)b_l*512
                 + ((size_t)(oct_p ^ b_l) << 2) + (size_t)((uu & 7) >> 1);
      hiw = mb1[ib1]; low = mb1[ib1 + 256];
      h1_reg = f16val((uint16_t)(hiw >> sh)) + f16val((uint16_t)(low >> sh)) * LOINV;
    }
#pragma unroll
    for (int g = 0; g < 4; ++g)
      b1g[g] = bih1[g*512 + hs*16 + uu] + bhh1[g*512 + hs*16 + uu];
    yfl = (size_t)(hs >> 1)*4096 + (size_t)bg*512 + (size_t)(uu & 1)*256
        + (size_t)((((hs & 1) << 1) | (uu >> 3)))*64 + (size_t)b_l*4
        + (size_t)((uu & 7) >> 1);
  }
  // GEMM-wave setup
  const int gw = wv - 4;
  const int mblk = blockIdx.x >> 4, nblk = blockIdx.x & 15;
  f32x4 ga0[2][2], ga1[2][2];
#pragma unroll
  for (int i = 0; i < 2; ++i)
#pragma unroll
    for (int j = 0; j < 2; ++j) { ga0[i][j] = (f32x4){0,0,0,0}; ga1[i][j] = (f32x4){0,0,0,0}; }

  asm volatile("s_waitcnt vmcnt(0)" ::: "memory");   // Wih1 LDS staging done
  __builtin_amdgcn_s_barrier();                        // pre-3
  __builtin_amdgcn_sched_barrier(0);

  for (int it = 0; it < nt; ++it) {
    const int t = s0 + it;
    const bool aL0 = (t < 256);
    const bool aL1 = (t > 0);

    uint16_t x0w[4] = {0,0,0,0};
    if (rec) {
      // Xg0 prefetch (fp16, overlaps flag wait)
      if (aL0) {
        const uint16_t* xgp = xg + ((size_t)it*128 + bglob)*2048 + hs*16 + uu;
        x0w[0] = xgp[0]; x0w[1] = xgp[512]; x0w[2] = xgp[1024]; x0w[3] = xgp[1536];
      }
      // concurrent polls: wave0 -> flg0 >= t, wave1 -> flg1 >= t-1 (L2-local)
      if (it > 0) {
        if (wv == 0) {
          const uint32_t* fp = flg0 + bg*32 + (lane & 31);
          while (1) {
            uint32_t f = __hip_atomic_load(fp, __ATOMIC_RELAXED, __HIP_MEMORY_SCOPE_AGENT);
            if (__all((int)(f >= (uint32_t)t))) break;
            __builtin_amdgcn_s_sleep(1);
          }
        } else if (wv == 1) {
          const uint32_t* fp = flg1 + bg*32 + (lane & 31);
          while (1) {
            uint32_t f = __hip_atomic_load(fp, __ATOMIC_RELAXED, __HIP_MEMORY_SCOPE_AGENT);
            if (__all((int)(f >= (uint32_t)(t - 1)))) break;
            __builtin_amdgcn_s_sleep(1);
          }
        }
      }
    } else if (doGemm && it < 64) {
      // ---- fused next-chunk GEMM slice: 2x2 frags, 4 k-slices per tick ----
      const int sf = it >> 2, ph = it & 3;
      const int mg = sf >> 2, ng = sf & 3;
      const int sstep = mblk*4 + gw;
      if (ph == 0) {
#pragma unroll
        for (int i = 0; i < 2; ++i)
#pragma unroll
          for (int j = 0; j < 2; ++j) { ga0[i][j] = (f32x4){0,0,0,0}; ga1[i][j] = (f32x4){0,0,0,0}; }
      }
      const uint32_t* ab = ApN + (size_t)sstep*65536 + (size_t)(mg*2)*512 + lane*4;
      const uint32_t* bb = Wp0 + (size_t)nblk*65536 + (size_t)(ng*2)*512 + lane*4;
#pragma unroll
      for (int kk = 0; kk < 4; ++kk) {
        const int kt = ph*4 + kk;
        uint4 gbh[2], gbl[2], gah[2], gal[2];
#pragma unroll
        for (int j = 0; j < 2; ++j) {
          gbh[j] = *(const uint4*)(bb + (size_t)kt*4096 + j*512);
          gbl[j] = *(const uint4*)(bb + (size_t)kt*4096 + j*512 + 256);
        }
#pragma unroll
        for (int i = 0; i < 2; ++i) {
          gah[i] = *(const uint4*)(ab + (size_t)kt*4096 + i*512);
          gal[i] = *(const uint4*)(ab + (size_t)kt*4096 + i*512 + 256);
        }
#pragma unroll
        for (int i = 0; i < 2; ++i)
#pragma unroll
          for (int j = 0; j < 2; ++j) {
            ga0[i][j] = mfma16(gah[i], gbh[j], ga0[i][j]);
            ga1[i][j] = mfma16(gal[i], gbh[j], ga1[i][j]);
            ga1[i][j] = mfma16(gah[i], gbl[j], ga1[i][j]);
          }
      }
      if (ph == 3) {
#pragma unroll
        for (int j = 0; j < 2; ++j) {
          const int col = nblk*128 + (ng*2 + j)*16 + (lane & 15);
          const float bias = bih0[col] + bhh0[col];
#pragma unroll
          for (int i = 0; i < 2; ++i) {
            const int rowb = sstep*128 + (mg*2 + i)*16 + ((lane >> 4) << 2);
#pragma unroll
            for (int r = 0; r < 4; ++r)
              XgN[(size_t)(rowb + r)*2048 + col] =
                hbits((f16)(ga0[i][j][r] + ga1[i][j][r]*LOINV + bias));
          }
        }
      }
    }
    __builtin_amdgcn_s_barrier();                      // (1) producers ready
    __builtin_amdgcn_sched_barrier(0);

    if (rec) { // stage BOTH tiles (independent buffers, one barrier)
      const uint64_t* sp0 = (const uint64_t*)(mb0 + (size_t)(t & 1)*65536 + bgoff);
      const uint64_t* sp1 = (const uint64_t*)(mb1 + (size_t)((t - 1) & 1)*65536 + bgoff);
      uint64_t v0[16], v1[16];
#pragma unroll
      for (int e = 0; e < 16; ++e)
        v0[e] = __hip_atomic_load(sp0 + tid + e*256, __ATOMIC_RELAXED, __HIP_MEMORY_SCOPE_AGENT);
      if (aL1) {
#pragma unroll
        for (int e = 0; e < 16; ++e)
          v1[e] = __hip_atomic_load(sp1 + tid + e*256, __ATOMIC_RELAXED, __HIP_MEMORY_SCOPE_AGENT);
      }
#pragma unroll
      for (int e = 0; e < 16; ++e)
        tA64[tid + e*256] = v0[e];
      if (aL1) {
#pragma unroll
        for (int e = 0; e < 16; ++e)
          tB64[tid + e*256] = v1[e];
      }
    }
    asm volatile("s_waitcnt lgkmcnt(0)" ::: "memory");
    __builtin_amdgcn_s_barrier();                      // (2) both tiles staged
    __builtin_amdgcn_sched_barrier(0);

    f32x4 A0 = (f32x4){0,0,0,0}, A1 = (f32x4){0,0,0,0}, A2 = (f32x4){0,0,0,0};
    f32x4 B0 = (f32x4){0,0,0,0}, B1 = (f32x4){0,0,0,0};
    if (rec) {
      {
        const uint8_t* hrp = tileA + (size_t)row*2048;
        const uint8_t* wbase = wih + (size_t)wv*16384;
        const bool cY = aL1 && ((t - 1) < lenA);
        const uint4 z4 = make_uint4(0,0,0,0);
#pragma unroll
        for (int kt = 0; kt < 16; ++kt) {
          int oct = kt*4 + qh;
          const uint8_t* pA = hrp + (((oct ^ row)) << 4);
          uint4 ah = *(const uint4*)pA, al = *(const uint4*)(pA + 1024);
          A0 = mfma16(ah, w0h[kt], A0);
          A1 = mfma16(al, w0h[kt], A1);
          A2 = mfma16(ah, w0l[kt], A2);
          uint4 yh = cY ? ah : z4, yl = cY ? al : z4;
          uint4 bh = *(const uint4*)(wbase + (size_t)kt*1024 + lane*16);
          B0 = mfma16(yh, bh, B0);
          B1 = mfma16(yl, bh, B1);
        }
      }
      if (aL1) {
        const uint8_t* hrp = tileB + (size_t)row*2048;
#pragma unroll
        for (int kt = 0; kt < 16; ++kt) {
          int oct = kt*4 + qh;
          const uint8_t* pA = hrp + (((oct ^ row)) << 4);
          uint4 ah = *(const uint4*)pA, al = *(const uint4*)(pA + 1024);
          B0 = mfma16(ah, w1h[kt], B0);
          B1 = mfma16(al, w1h[kt], B1);
        }
      }
      // gate exchange (dedicated region; own-wave data only)
      {
        int col = lane & 15, rb = (lane >> 4) << 2;
        if (aL0) {
#pragma unroll
          for (int r = 0; r < 4; ++r)
            g0ex[(size_t)(wv*16 + rb + r)*16 + col] = A0[r] + (A1[r] + A2[r])*LOINV;
        }
        if (aL1) {
#pragma unroll
          for (int r = 0; r < 4; ++r)
            g1ex[(size_t)(wv*16 + rb + r)*16 + col] = B0[r] + B1[r]*LOINV;
        }
      }
    }
    asm volatile("s_waitcnt lgkmcnt(0)" ::: "memory");
    __builtin_amdgcn_s_barrier();                      // (3) gates exchanged
    __builtin_amdgcn_sched_barrier(0);

    uint32_t p1w = 0; bool m1 = false;
    if (rec) {
      if (aL0) {
        float gi = g0ex[(size_t)(0*16 + b_l)*16 + uu] + f16val(x0w[0]);
        float gf = g0ex[(size_t)(1*16 + b_l)*16 + uu] + f16val(x0w[1]);
        float gg = g0ex[(size_t)(2*16 + b_l)*16 + uu] + f16val(x0w[2]);
        float go = g0ex[(size_t)(3*16 + b_l)*16 + uu] + f16val(x0w[3]);
        float cn = fsigm(gf)*c0_reg + fsigm(gi)*ftanh(gg);
        float hn = fsigm(go)*ftanh(cn);
        bool m = (t < len_b);
        c0_reg = m ? cn : c0_reg;
        h0_reg = m ? hn : h0_reg;
        uint32_t p = split_ph2(h0_reg);
        uint32_t pp = __shfl_xor(p, 1);
        __hip_atomic_store(mb0 + (size_t)((t + 1) & 1)*65536 + bgoff + widx,
                           plane_word(p, pp, uu & 1), __ATOMIC_RELAXED, __HIP_MEMORY_SCOPE_AGENT);
      }
      if (aL1) {
        float gi = g1ex[(size_t)(0*16 + b_l)*16 + uu] + b1g[0];
        float gf = g1ex[(size_t)(1*16 + b_l)*16 + uu] + b1g[1];
        float gg = g1ex[(size_t)(2*16 + b_l)*16 + uu] + b1g[2];
        float go = g1ex[(size_t)(3*16 + b_l)*16 + uu] + b1g[3];
        float cn = fsigm(gf)*c1_reg + fsigm(gi)*ftanh(gg);
        float hn = fsigm(go)*ftanh(cn);
        m1 = ((t - 1) < len_b);
        c1_reg = m1 ? cn : c1_reg;
        h1_reg = m1 ? hn : h1_reg;
        uint32_t p = split_ph2(h1_reg);
        uint32_t pp = __shfl_xor(p, 1);
        p1w = plane_word(p, pp, uu & 1);
        __hip_atomic_store(mb1 + (size_t)(t & 1)*65536 + bgoff + widx,
                           p1w, __ATOMIC_RELAXED, __HIP_MEMORY_SCOPE_AGENT);
      }
    }
    asm volatile("s_waitcnt vmcnt(0)" ::: "memory");
    __builtin_amdgcn_s_barrier();                      // (4) publishes in L2
    __builtin_amdgcn_sched_barrier(0);
    if (rec) {
      if (tid == 0) {
        if (aL0) __hip_atomic_store(flg0 + bg*32 + hs, (uint32_t)(t + 1),
                                    __ATOMIC_RELAXED, __HIP_MEMORY_SCOPE_AGENT);
        if (aL1) __hip_atomic_store(flg1 + bg*32 + hs, (uint32_t)t,
                                    __ATOMIC_RELAXED, __HIP_MEMORY_SCOPE_AGENT);
      }
      if (aL1) y1buf[(size_t)(t - 1)*65536 + yfl] = m1 ? p1w : 0u;
    }
  }
  if (rec) {
    cb0[(size_t)bglob*512 + hs*16 + uu] = c0_reg;
    cb1[(size_t)bglob*512 + hs*16 + uu] = c1_reg;
  }
}

// ---------------------------------------------------------------------------
// small epilogue kernels
// ---------------------------------------------------------------------------
__global__ __launch_bounds__(256) void k_pack2(const float* __restrict__ a,
    const float* __restrict__ b, uint32_t* __restrict__ out)
{
  int i = blockIdx.x*256 + threadIdx.x;
  int bb = i >> 10, k = i & 1023;
  float x = (k < 512) ? a[(size_t)bb*512 + k] : b[(size_t)bb*512 + k - 512];
  out[i] = split_ph2(x);
}

__global__ __launch_bounds__(256) void k_tanh_split(const float* __restrict__ c,
    uint32_t* __restrict__ hp)
{ int i = blockIdx.x*256 + threadIdx.x; hp[i] = split_ph2(tanhf(c[i])); }

__global__ __launch_bounds__(256) void k_dec_cell(const float* __restrict__ g,
    const float* __restrict__ cdec, float* __restrict__ hout, float* __restrict__ dh)
{
  int i = blockIdx.x*256 + threadIdx.x;     // 65536
  int b = i >> 9, u = i & 511;
  const float* gb = g + (size_t)b*2048;
  float c = sigm(gb[512 + u])*cdec[i] + sigm(gb[u])*tanhf(gb[1024 + u]);
  float h = sigm(gb[1536 + u])*tanhf(c);
  hout[i] = h; dh[i] = h;
}

// scores -> masked softmax -> context; y1 is in fl layout
__global__ __launch_bounds__(256) void k_attn(const uint32_t* __restrict__ y1,
    const float* __restrict__ h, const int* __restrict__ lens,
    float* __restrict__ ctx, float* __restrict__ dctx)
{
  __shared__ float hsh[512];
  __shared__ float sc[256];
  __shared__ float red[8];
  const int b = blockIdx.x, tid = threadIdx.x, lane = tid & 63, wv = tid >> 6;
  hsh[tid]       = h[(size_t)b*512 + tid];
  hsh[tid + 256] = h[(size_t)b*512 + tid + 256];
  const int len = lens[b];
  __syncthreads();

  const size_t lanebase = (size_t)(lane >> 2)*4096 + (size_t)(b >> 4)*512
                        + (size_t)(lane & 3)*64 + (size_t)(b & 15)*4;
  for (int it = 0; it < 64; ++it) {
    int s = wv*64 + it;
    const uint32_t* yb = y1 + (size_t)s*65536 + lanebase;
    uint4 hw = *(const uint4*)yb;
    uint4 lw = *(const uint4*)(yb + 256);
    int k0 = lane*8;
    uint32_t hws[4] = {hw.x,hw.y,hw.z,hw.w}, lws[4] = {lw.x,lw.y,lw.z,lw.w};
    float d = 0.f;
#pragma unroll
    for (int w = 0; w < 4; ++w) {
      d += (f16val((uint16_t)hws[w]) + f16val((uint16_t)lws[w])*LOINV) * hsh[k0 + 2*w]
         + (f16val((uint16_t)(hws[w]>>16)) + f16val((uint16_t)(lws[w]>>16))*LOINV) * hsh[k0 + 2*w + 1];
    }
    for (int off = 32; off; off >>= 1) d += __shfl_xor(d, off);
    if (lane == 0) sc[s] = d;
  }
  __syncthreads();

  float v = (tid < len) ? sc[tid] : -INFINITY;
  float mx = v;
  for (int off = 32; off; off >>= 1) mx = fmaxf(mx, __shfl_xor(mx, off));
  if (lane == 0) red[wv] = mx;
  __syncthreads();
  mx = fmaxf(fmaxf(red[0], red[1]), fmaxf(red[2], red[3]));
  float e = (tid < len) ? expf(v - mx) : 0.f;
  float ssum = e;
  for (int off = 32; off; off >>= 1) ssum += __shfl_xor(ssum, off);
  if (lane == 0) red[4 + wv] = ssum;
  __syncthreads();
  float tot = red[4] + red[5] + red[6] + red[7];
  __syncthreads();
  sc[tid] = e / tot;
  __syncthreads();

  const int u0 = tid, u1 = tid + 256;
  const size_t bu0 = (size_t)(u0 >> 5)*4096 + (size_t)(b >> 4)*512
                   + (size_t)((u0 >> 3) & 3)*64 + (size_t)(b & 15)*4 + (size_t)((u0 & 7) >> 1);
  const size_t bu1 = (size_t)(u1 >> 5)*4096 + (size_t)(b >> 4)*512
                   + (size_t)((u1 >> 3) & 3)*64 + (size_t)(b & 15)*4 + (size_t)((u1 & 7) >> 1);
  const int sh = (tid & 1) * 16;
  float acc0 = 0.f, acc1 = 0.f;
  for (int s = 0; s < 256; ++s) {
    float w = sc[s];
    const uint32_t* yb = y1 + (size_t)s*65536;
    uint32_t hi0 = yb[bu0], lo0 = yb[bu0 + 256];
    uint32_t hi1 = yb[bu1], lo1 = yb[bu1 + 256];
    acc0 += w*(f16val((uint16_t)(hi0 >> sh)) + f16val((uint16_t)(lo0 >> sh))*LOINV);
    acc1 += w*(f16val((uint16_t)(hi1 >> sh)) + f16val((uint16_t)(lo1 >> sh))*LOINV);
  }
  ctx [(size_t)b*512 + tid]       = acc0;  ctx [(size_t)b*512 + tid + 256] = acc1;
  dctx[(size_t)b*512 + tid]       = acc0;  dctx[(size_t)b*512 + tid + 256] = acc1;
}

__global__ __launch_bounds__(256) void k_argmax(const float* __restrict__ logits,
    float* __restrict__ out)
{
  __shared__ float bv[256];
  __shared__ int   bi[256];
  const int b = blockIdx.x, tid = threadIdx.x;
  const float* L = logits + (size_t)b*32000;
  float best = -INFINITY; int idx = 0;
  for (int i = tid; i < 32000; i += 256) {
    float v = L[i];
    if (v > best) { best = v; idx = i; }
  }
  bv[tid] = best; bi[tid] = idx;
  __syncthreads();
  for (int sft = 128; sft; sft >>= 1) {
    if (tid < sft) {
      if (bv[tid+sft] > bv[tid] || (bv[tid+sft] == bv[tid] && bi[tid+sft] < bi[tid])) {
        bv[tid] = bv[tid+sft]; bi[tid] = bi[tid+sft];
      }
    }
    __syncthreads();
  }
  if (tid == 0) out[b] = (float)bi[0];
}

// ---------------------------------------------------------------------------
// launcher
// ---------------------------------------------------------------------------
extern "C" void kernel_launch(void* const* d_in, const int* in_sizes, int n_in,
                              void* d_out, int out_size, void* d_ws, size_t ws_size,
                              hipStream_t stream)
{
  (void)in_sizes; (void)n_in; (void)out_size; (void)ws_size;
  const int*   src_tokens = (const int*)  d_in[0];
  const int*   src_lens   = (const int*)  d_in[1];
  const int*   trg_tokens = (const int*)  d_in[2];
  const float* src_emb    = (const float*)d_in[3];
  const float* trg_emb    = (const float*)d_in[4];
  const float* Wih0 = (const float*)d_in[5];
  const float* Whh0 = (const float*)d_in[6];
  const float* bih0 = (const float*)d_in[7];
  const float* bhh0 = (const float*)d_in[8];
  const float* Wih1 = (const float*)d_in[9];
  const float* Whh1 = (const float*)d_in[10];
  const float* bih1 = (const float*)d_in[11];
  const float* bhh1 = (const float*)d_in[12];
  const float* dWih = (const float*)d_in[13];
  const float* dWhh = (const float*)d_in[14];
  const float* dbih = (const float*)d_in[15];
  const float* dbhh = (const float*)d_in[16];
  const float* Winit= (const float*)d_in[17];
  const float* binit= (const float*)d_in[18];
  const float* Whid = (const float*)d_in[19];
  const float* bhid = (const float*)d_in[20];
  const float* Wout = (const float*)d_in[21];
  const float* bout = (const float*)d_in[22];

  uint8_t* ws = (uint8_t*)d_ws;
  constexpr size_t MBs = 1ull << 20;
  constexpr size_t OFF_AP    = 0;                         // 64MB fl src embeds
  constexpr size_t OFF_Y1    = 64*MBs;                    // 64MB fl y1
  constexpr size_t OFF_XG    = 128*MBs;                   // 2x32MB fp16 Xg ping-pong
  constexpr size_t OFF_MB    = 192*MBs;                   // 1MB: mb0 | mb1
  constexpr size_t OFF_CB0   = OFF_MB    + 1*MBs;
  constexpr size_t OFF_CB1   = OFF_CB0   + 256*1024;
  constexpr size_t OFF_FLG   = OFF_CB1   + 256*1024;      // flg0 | claim(+1024) | flg1(+2048)
  constexpr size_t OFF_PK    = OFF_FLG   + 4096;
  constexpr size_t OFF_CDEC  = OFF_PK    + 512*1024;
  constexpr size_t OFF_HDECP = OFF_CDEC  + 256*1024;
  constexpr size_t OFF_EMBP  = OFF_HDECP + 256*1024;
  constexpr size_t OFF_G     = OFF_EMBP  + 256*1024;
  constexpr size_t OFF_HDEC2 = OFF_G     + 1*MBs;
  constexpr size_t OFF_CTX   = OFF_HDEC2 + 256*1024;
  constexpr size_t OFF_AVEC  = OFF_CTX   + 256*1024;
  constexpr size_t OFF_AVECP = OFF_AVEC  + 256*1024;
  constexpr size_t OFF_LOG   = OFF_AVECP + 256*1024;      // 16MB logits; Wp0/Wp1 overlay

  uint32_t* Ap    = (uint32_t*)(ws + OFF_AP);
  uint32_t* Y1    = (uint32_t*)(ws + OFF_Y1);
  uint16_t* Xg0   = (uint16_t*)(ws + OFF_XG);
  uint16_t* Xg1   = (uint16_t*)(ws + OFF_XG + 32*MBs);
  uint32_t* mb0   = (uint32_t*)(ws + OFF_MB);
  uint32_t* mb1   = (uint32_t*)(ws + OFF_MB + 512*1024);
  float*    cb0   = (float*)   (ws + OFF_CB0);
  float*    cb1   = (float*)   (ws + OFF_CB1);
  uint32_t* flg0  = (uint32_t*)(ws + OFF_FLG);
  uint32_t* xclm  = (uint32_t*)(ws + OFF_FLG + 1024);
  uint32_t* flg1  = (uint32_t*)(ws + OFF_FLG + 2048);
  uint32_t* pk    = (uint32_t*)(ws + OFF_PK);
  float*    cdec  = (float*)   (ws + OFF_CDEC);
  uint32_t* hdecp = (uint32_t*)(ws + OFF_HDECP);
  uint32_t* embp  = (uint32_t*)(ws + OFF_EMBP);
  float*    g     = (float*)   (ws + OFF_G);
  float*    hdec2 = (float*)   (ws + OFF_HDEC2);
  float*    ctx   = (float*)   (ws + OFF_CTX);
  float*    avec  = (float*)   (ws + OFF_AVEC);
  uint32_t* avecp = (uint32_t*)(ws + OFF_AVECP);
  float*    logit = (float*)   (ws + OFF_LOG);
  uint32_t* Wp0   = (uint32_t*)(ws + OFF_LOG);            // overlays logits
  uint32_t* Wp1   = (uint32_t*)(ws + OFF_LOG + 4*MBs);
  float*    dout  = (float*)   d_out;

  // ---- pre-split encoder input weights to fl ----
  k_packW<<<4096, 256, 0, stream>>>(Wih0, Wp0);
  k_packW<<<4096, 256, 0, stream>>>(Wih1, Wp1);

  // ---- encoder: fused two-layer pipeline + in-kernel next-chunk GEMM ----
  hipMemsetAsync(mb0,  0, 1024*1024, stream);   // both mailboxes -> h(0)=0
  hipMemsetAsync(flg0, 0, 4096, stream);        // flags + claim counters
  hipMemsetAsync(cb0,  0, 65536*4, stream);
  hipMemsetAsync(cb1,  0, 65536*4, stream);
  k_embed_src_fl<<<2048, 256, 0, stream>>>(src_tokens, src_emb, Ap);
  k_gemm_fl<<<dim3(16, 64), 256, 0, stream>>>(Ap, Wp0, bih0, bhh0,
      (float*)Xg0, 2048, 0, 2);                 // chunk 0 Xg
  for (int c = 0; c < 4; ++c) {
    int s0 = c * 64;
    uint16_t* xgCur = (c & 1) ? Xg1 : Xg0;
    uint16_t* xgNxt = (c & 1) ? Xg0 : Xg1;
    const uint32_t* apN = (c < 3) ? (Ap + (size_t)(c + 1)*64*65536) : Ap;
    k_lstm2<<<256, 512, 0, stream>>>(Whh0, Whh1, bih1, bhh1, xgCur, src_lens,
        mb0, mb1, cb0, cb1, Y1, flg0, flg1, xclm, Wp1,
        Wp0, apN, xgNxt, bih0, bhh0, (c < 3) ? 1 : 0,
        s0, (c == 3) ? 65 : 64);
  }

  // ---- decoder init ----
  k_pack2<<<512, 256, 0, stream>>>(cb0, cb1, pk);
  k_gemm<<<dim3(4, 1), 256, 0, stream>>>(pk, 1024, Winit, 1024, binit, nullptr,
      cdec, 512, 1024, 0);
  k_tanh_split<<<256, 256, 0, stream>>>(cdec, hdecp);

  // ---- decoder LSTM step ----
  k_embed_trg<<<256, 256, 0, stream>>>(trg_tokens, trg_emb, embp);
  k_gemm<<<dim3(16, 1), 256, 0, stream>>>(embp, 512, dWih, 1024, dbih, dbhh,
      g, 2048, 512, 0);
  k_gemm<<<dim3(16, 1), 256, 0, stream>>>(hdecp, 512, dWhh, 512, nullptr, nullptr,
      g, 2048, 512, 1);
  k_dec_cell<<<256, 256, 0, stream>>>(g, cdec, hdec2, dout + 65536);

  // ---- attention (fl reads) ----
  k_attn<<<128, 256, 0, stream>>>(Y1, hdec2, src_lens, ctx, dout);

  // ---- output projection + argmax (Wout read directly as f32) ----
  k_pack2<<<512, 256, 0, stream>>>(hdec2, ctx, pk);
  k_gemm<<<dim3(4, 1), 256, 0, stream>>>(pk, 1024, Whid, 1024, bhid, nullptr,
      avec, 512, 1024, 0);
  k_pack1<<<256, 256, 0, stream>>>(avec, avecp);
  k_gemm<<<dim3(250, 1), 256, 0, stream>>>(avecp, 512, Wout, 512, bout, nullptr,
      logit, 32000, 512, 0);
  k_argmax<<<128, 256, 0, stream>>>(logit, dout + 131072);
}

// Round 18
// 2363.892 us; speedup vs baseline: 2.1882x; 2.1882x over previous
//
#include <hip/hip_runtime.h>
#include <stdint.h>

// ---------------------------------------------------------------------------
// Seq2seq (2-layer LSTM encoder + attention decoder) on MI355X.
// Numerics: "ph2" split-fp16: value = hi(f16) + lo(f16) * 2^-11; GEMMs do 3
// MFMA products (hi*hi -> acc0, lo*hi + hi*lo -> acc1, result acc0+acc1/2048).
// FINAL (round-16 champion, 2368us): fused two-layer recurrence (4-barrier
// tick, XCD-local rings, agent-scope mailboxes, Whh in AGPRs, Wih1 hi-plane
// in LDS), fp16 Xg, fl-layout GEMMs with global_load_lds staging, direct-f32
// logits GEMM. Round-17 wave-specialization reverted (register-budget spill).
// ---------------------------------------------------------------------------

typedef _Float16 f16;
typedef f16 f16x8 __attribute__((ext_vector_type(8)));
typedef float f32x4 __attribute__((ext_vector_type(4)));

#define LOSCALE 2048.0f
#define LOINV   (1.0f/2048.0f)

#define B_  128
#define S_  256
#define H_  512

__device__ __forceinline__ uint16_t hbits(f16 h){ union{ f16 f; uint16_t u; } c; c.f=h; return c.u; }
__device__ __forceinline__ float f16val(uint16_t u){ union{ uint16_t u; f16 f; } c; c.u=u; return (float)c.f; }

__device__ __forceinline__ uint32_t split_ph2(float x){
  f16 h = (f16)x;
  float r = (x - (float)h) * LOSCALE;
  return (uint32_t)hbits(h) | ((uint32_t)hbits((f16)r) << 16);
}
__device__ __forceinline__ float ph2val(uint32_t p){
  union{ uint16_t u; f16 f; } a, b; a.u = (uint16_t)p; b.u = (uint16_t)(p>>16);
  return (float)a.f + (float)b.f * LOINV;
}

__device__ __forceinline__ void pack_hi_lo(const uint4& a, const uint4& b, uint4& hi, uint4& lo){
  hi = make_uint4((a.x & 0xffffu) | (a.y << 16),
                  (a.z & 0xffffu) | (a.w << 16),
                  (b.x & 0xffffu) | (b.y << 16),
                  (b.z & 0xffffu) | (b.w << 16));
  lo = make_uint4((a.x >> 16) | (a.y & 0xffff0000u),
                  (a.z >> 16) | (a.w & 0xffff0000u),
                  (b.x >> 16) | (b.y & 0xffff0000u),
                  (b.z >> 16) | (b.w & 0xffff0000u));
}

__device__ __forceinline__ void split_pack8(const float* x, uint4& hi, uint4& lo){
  uint16_t h[8], l[8];
#pragma unroll
  for (int e = 0; e < 8; ++e) {
    f16 hh = (f16)x[e];
    float r = (x[e] - (float)hh) * LOSCALE;
    h[e] = hbits(hh); l[e] = hbits((f16)r);
  }
  hi = make_uint4((uint32_t)h[0]|((uint32_t)h[1]<<16), (uint32_t)h[2]|((uint32_t)h[3]<<16),
                  (uint32_t)h[4]|((uint32_t)h[5]<<16), (uint32_t)h[6]|((uint32_t)h[7]<<16));
  lo = make_uint4((uint32_t)l[0]|((uint32_t)l[1]<<16), (uint32_t)l[2]|((uint32_t)l[3]<<16),
                  (uint32_t)l[4]|((uint32_t)l[5]<<16), (uint32_t)l[6]|((uint32_t)l[7]<<16));
}

__device__ __forceinline__ f32x4 mfma16(uint4 a, uint4 b, f32x4 c){
  return __builtin_amdgcn_mfma_f32_16x16x32_f16(
      __builtin_bit_cast(f16x8, a), __builtin_bit_cast(f16x8, b), c, 0, 0, 0);
}

__device__ __forceinline__ float sigm(float x){ return 1.0f/(1.0f + expf(-x)); }
__device__ __forceinline__ float fsigm(float x){ return 1.0f/(1.0f + __expf(-x)); }
__device__ __forceinline__ float ftanh(float x){
  float ax = fabsf(x);
  float e = __expf(-2.0f*ax);
  float r = (1.0f - e)/(1.0f + e);
  return copysignf(r, x);
}

__device__ __forceinline__ uint32_t plane_word(uint32_t p, uint32_t pp, int odd){
  return odd ? ((pp >> 16) | (p & 0xffff0000u))
             : ((p & 0xffffu) | (pp << 16));
}

__device__ __forceinline__ size_t fl_idx(int row, int k){
  return (size_t)(k >> 5) * 4096 + (size_t)(row >> 4) * 512 + (size_t)(k & 1) * 256
       + (size_t)((k >> 3) & 3) * 64 + (size_t)(row & 15) * 4 + (size_t)((k & 7) >> 1);
}

__device__ __forceinline__ void gload_lds16(const uint32_t* gbase, uint32_t* lbase, int lane){
#if __has_builtin(__builtin_amdgcn_global_load_lds)
  __builtin_amdgcn_global_load_lds(
      (const __attribute__((address_space(1))) uint32_t*)(gbase + lane*4),
      (__attribute__((address_space(3))) uint32_t*)lbase, 16, 0, 0);
#else
  *(uint4*)(lbase + lane*4) = *(const uint4*)(gbase + lane*4);
#endif
}

// ---------------------------------------------------------------------------
// K1: embedding gather -> fl layout
// ---------------------------------------------------------------------------
__global__ __launch_bounds__(256) void k_embed_src_fl(const int* __restrict__ tok,
    const float* __restrict__ emb, uint32_t* __restrict__ out)
{
  const size_t total = (size_t)S_ * B_ * H_;
  for (size_t i = (size_t)blockIdx.x*256 + threadIdx.x; i < total; i += (size_t)gridDim.x*256) {
    int s = (int)(i >> 16), b = (int)((i >> 9) & 127), k = (int)(i & 511);
    int t = tok[b*S_ + s];
    uint32_t p = split_ph2(emb[(size_t)t*H_ + k]);
    uint32_t pp = __shfl_xor(p, 1);
    out[(size_t)s*65536 + fl_idx(b, k)] = plane_word(p, pp, k & 1);
  }
}

__global__ __launch_bounds__(256) void k_embed_trg(const int* __restrict__ tok,
    const float* __restrict__ emb, uint32_t* __restrict__ out)
{
  int i = blockIdx.x*256 + threadIdx.x;   // 65536
  int e = i & (H_-1), b = i >> 9;
  int t = tok[b];
  out[i] = split_ph2(emb[(size_t)t*H_ + e]);
}

// W f32 [N][512] -> fl ph2
__global__ __launch_bounds__(256) void k_packW(const float* __restrict__ W,
    uint32_t* __restrict__ out)
{
  int i = blockIdx.x*256 + threadIdx.x;
  int n = i >> 9, k = i & 511;
  uint32_t p = split_ph2(W[i]);
  uint32_t pp = __shfl_xor(p, 1);
  out[(size_t)(n >> 7)*65536 + fl_idx(n & 127, k)] = plane_word(p, pp, k & 1);
}

// a f32 -> linear ph2
__global__ __launch_bounds__(256) void k_pack1(const float* __restrict__ a,
    uint32_t* __restrict__ out)
{ int i = blockIdx.x*256 + threadIdx.x; out[i] = split_ph2(a[i]); }

// ---------------------------------------------------------------------------
// K2a: fl GEMM — staging via global_load_lds, zero repack VALU. K=512.
// outMode: 0 = f32 C, 2 = fp16 C (u16/elem; addC must be 0 for mode 2).
// ---------------------------------------------------------------------------
__global__ __launch_bounds__(256,2) void k_gemm_fl(
    const uint32_t* __restrict__ Afl,
    const uint32_t* __restrict__ Wfl,
    const float* __restrict__ b0, const float* __restrict__ b1,
    float* __restrict__ C, int N, int addC, int outMode)
{
  __shared__ uint8_t sm[65536];
  const int tid = threadIdx.x, lane = tid & 63, wv = tid >> 6;
  const int wm = wv >> 1, wn = wv & 1;
  const int bn0 = blockIdx.x * 128, bm0 = blockIdx.y * 128;
  const uint32_t* Ab = Afl + (size_t)blockIdx.y * 65536;
  const uint32_t* Wb = Wfl + (size_t)blockIdx.x * 65536;

  f32x4 acc0[4][4], acc1[4][4];
#pragma unroll
  for (int i = 0; i < 4; ++i)
#pragma unroll
    for (int j = 0; j < 4; ++j) { acc0[i][j] = (f32x4){0,0,0,0}; acc1[i][j] = (f32x4){0,0,0,0}; }

  for (int it = 0; it < 8; ++it) {
    __syncthreads();
    {
      const uint32_t* gsrc = (wv < 2 ? Ab : Wb) + (size_t)it*8192 + (size_t)(wv & 1)*4096;
      uint32_t* lb = (uint32_t*)(sm + (size_t)wv*16384);
#pragma unroll
      for (int e = 0; e < 16; ++e)
        gload_lds16(gsrc + e*256, lb + e*256, lane);
    }
    asm volatile("s_waitcnt vmcnt(0)" ::: "memory");
    __syncthreads();

#pragma unroll
    for (int kt = 0; kt < 2; ++kt) {
      uint4 ah[4], al[4];
#pragma unroll
      for (int i = 0; i < 4; ++i) {
        const uint8_t* p = sm + (size_t)(kt*8 + wm*4 + i)*2048 + lane*16;
        ah[i] = *(const uint4*)p; al[i] = *(const uint4*)(p + 1024);
      }
#pragma unroll
      for (int j = 0; j < 4; ++j) {
        const uint8_t* p = sm + 32768 + (size_t)(kt*8 + wn*4 + j)*2048 + lane*16;
        uint4 bh = *(const uint4*)p;
        uint4 bl = *(const uint4*)(p + 1024);
#pragma unroll
        for (int i = 0; i < 4; ++i) {
          acc0[i][j] = mfma16(ah[i], bh, acc0[i][j]);
          acc1[i][j] = mfma16(al[i], bh, acc1[i][j]);
          acc1[i][j] = mfma16(ah[i], bl, acc1[i][j]);
        }
      }
    }
  }

#pragma unroll
  for (int i = 0; i < 4; ++i) {
    int row0 = bm0 + (wm*4+i)*16 + ((lane>>4)<<2);
#pragma unroll
    for (int j = 0; j < 4; ++j) {
      int col = bn0 + (wn*4+j)*16 + (lane & 15);
      float bias = 0.f;
      if (b0) bias += b0[col];
      if (b1) bias += b1[col];
      f32x4 v = acc0[i][j] + acc1[i][j] * LOINV;
#pragma unroll
      for (int r = 0; r < 4; ++r) {
        size_t idx = (size_t)(row0 + r) * N + col;
        float out = v[r] + bias;
        if (addC) out += C[idx];
        if (outMode == 2) ((uint16_t*)C)[idx] = hbits((f16)out);
        else              C[idx] = out;
      }
    }
  }
}

// ---------------------------------------------------------------------------
// K2b: legacy GEMM (f32 weights, linear ph2 A) — decoder matmuls + logits
// ---------------------------------------------------------------------------
__global__ __launch_bounds__(256,2) void k_gemm(
    const uint32_t* __restrict__ A, int lda,
    const float* __restrict__ W, int ldw,
    const float* __restrict__ b0, const float* __restrict__ b1,
    float* __restrict__ C, int N, int K, int addC)
{
  __shared__ uint8_t sm[65536];
  const int tid = threadIdx.x;
  const int lane = tid & 63, wv = tid >> 6;
  const int wm = wv >> 1, wn = wv & 1;
  const int bn0 = blockIdx.x * 128, bm0 = blockIdx.y * 128;

  const int srow = tid >> 1;
  const int skh  = (tid & 1) * 32;
  const int smt  = srow >> 4, sr = srow & 15, skt = tid & 1;

  f32x4 acc0[4][4], acc1[4][4];
#pragma unroll
  for (int i = 0; i < 4; ++i)
#pragma unroll
    for (int j = 0; j < 4; ++j) { acc0[i][j] = (f32x4){0,0,0,0}; acc1[i][j] = (f32x4){0,0,0,0}; }

  for (int k0 = 0; k0 < K; k0 += 64) {
    __syncthreads();
    {
      const uint32_t* ap = A + (size_t)(bm0 + srow) * lda + (k0 + skh);
      uint4 q[8];
#pragma unroll
      for (int e = 0; e < 8; ++e) q[e] = *(const uint4*)(ap + e*4);
#pragma unroll
      for (int kg = 0; kg < 4; ++kg) {
        uint4 hi, lo; pack_hi_lo(q[2*kg], q[2*kg+1], hi, lo);
        uint8_t* dst = sm + (size_t)(smt*2 + skt)*2048 + (size_t)(sr + 16*kg)*16;
        *(uint4*)dst = hi; *(uint4*)(dst + 1024) = lo;
      }
    }
    {
      const float* wp = W + (size_t)(bn0 + srow) * ldw + (k0 + skh);
      float xs[32];
#pragma unroll
      for (int e = 0; e < 8; ++e) { float4 v = *(const float4*)(wp + e*4);
        xs[e*4+0]=v.x; xs[e*4+1]=v.y; xs[e*4+2]=v.z; xs[e*4+3]=v.w; }
#pragma unroll
      for (int kg = 0; kg < 4; ++kg) {
        uint4 hi, lo; split_pack8(xs + kg*8, hi, lo);
        uint8_t* dst = sm + 32768 + (size_t)(smt*2 + skt)*2048 + (size_t)(sr + 16*kg)*16;
        *(uint4*)dst = hi; *(uint4*)(dst + 1024) = lo;
      }
    }
    __syncthreads();

#pragma unroll
    for (int kt = 0; kt < 2; ++kt) {
      uint4 ah[4], al[4];
#pragma unroll
      for (int i = 0; i < 4; ++i) {
        const uint8_t* p = sm + (size_t)(((wm*4+i)*2 + kt))*2048 + lane*16;
        ah[i] = *(const uint4*)p; al[i] = *(const uint4*)(p + 1024);
      }
#pragma unroll
      for (int j = 0; j < 4; ++j) {
        const uint8_t* p = sm + 32768 + (size_t)(((wn*4+j)*2 + kt))*2048 + lane*16;
        uint4 bh = *(const uint4*)p;
        uint4 bl = *(const uint4*)(p + 1024);
#pragma unroll
        for (int i = 0; i < 4; ++i) {
          acc0[i][j] = mfma16(ah[i], bh, acc0[i][j]);
          acc1[i][j] = mfma16(al[i], bh, acc1[i][j]);
          acc1[i][j] = mfma16(ah[i], bl, acc1[i][j]);
        }
      }
    }
  }

#pragma unroll
  for (int i = 0; i < 4; ++i) {
    int row0 = bm0 + (wm*4+i)*16 + ((lane>>4)<<2);
#pragma unroll
    for (int j = 0; j < 4; ++j) {
      int col = bn0 + (wn*4+j)*16 + (lane & 15);
      float bias = 0.f;
      if (b0) bias += b0[col];
      if (b1) bias += b1[col];
      f32x4 v = acc0[i][j] + acc1[i][j] * LOINV;
#pragma unroll
      for (int r = 0; r < 4; ++r) {
        size_t idx = (size_t)(row0 + r) * N + col;
        float out = v[r] + bias;
        if (addC) out += C[idx];
        C[idx] = out;
      }
    }
  }
}

// ---------------------------------------------------------------------------
// K3: FUSED two-layer recurrence, 4-barrier tick (round-15 champion),
// Xg read as fp16.
// ---------------------------------------------------------------------------
__global__ __launch_bounds__(256,1) void k_lstm2(
    const float* __restrict__ Whh0, const float* __restrict__ Whh1,
    const float* __restrict__ bih1, const float* __restrict__ bhh1,
    const uint16_t* __restrict__ xg,      // [64][128][2048] fp16 (L0 chunk)
    const int*  __restrict__ lens,
    uint32_t* __restrict__ mb0,           // [2][8][8192] u32
    uint32_t* __restrict__ mb1,
    float* __restrict__ cb0, float* __restrict__ cb1,
    uint32_t* __restrict__ y1buf,         // fl [256][65536]
    uint32_t* __restrict__ flg0, uint32_t* __restrict__ flg1,   // [8][32]
    uint32_t* __restrict__ xcdclaim,      // [8] at stride 16 u32
    const uint32_t* __restrict__ Wp1,     // fl [16][65536]
    int s0, int nt)
{
  __shared__ uint8_t sm[139264];
  uint8_t* wih   = sm;                      // 64KB Wih1 hi-plane frags
  uint8_t* tileA = sm + 65536;              // 32KB h0 tile
  uint8_t* tileB = sm + 98304;              // 32KB h1 tile
  uint64_t* tA64 = (uint64_t*)tileA;
  uint64_t* tB64 = (uint64_t*)tileB;
  float* g0ex = (float*)(sm + 131072);      // 4KB (dedicated)
  float* g1ex = (float*)(sm + 135168);      // 4KB (dedicated)

  const int tid = threadIdx.x, lane = tid & 63, wv = tid >> 6;
  const int row = lane & 15, qh = lane >> 4;

  // ---- runtime role claim: ring = physical XCD, slot = claim order ----
  uint32_t* claim_sh = (uint32_t*)tileA;
  if (tid == 0) {
    uint32_t xcd;
    asm volatile("s_getreg_b32 %0, hwreg(HW_REG_XCC_ID)" : "=s"(xcd));
    xcd &= 7u;
    uint32_t pos = __hip_atomic_fetch_add(xcdclaim + xcd*16, 1u,
                     __ATOMIC_RELAXED, __HIP_MEMORY_SCOPE_SYSTEM);
    claim_sh[0] = xcd | ((pos & 31u) << 8);
  }
  __syncthreads();
  const uint32_t cl = claim_sh[0];
  const int bg = (int)(cl & 7u), hs = (int)((cl >> 8) & 31u);
  __syncthreads();

  // ---- Wih1 slice (hi plane only) -> LDS via global_load_lds ----
  {
    const uint32_t* wpb = Wp1 + (size_t)(wv*4 + (hs >> 3))*65536 + (size_t)(hs & 7)*512;
    uint32_t* lb = (uint32_t*)(wih + (size_t)wv*16384);
#pragma unroll
    for (int kt = 0; kt < 16; ++kt)
      gload_lds16(wpb + kt*4096, lb + kt*256, lane);
  }

  // ---- Whh0, Whh1 slices -> registers/AGPRs ----
  uint4 w0h[16], w0l[16], w1h[16], w1l[16];
  {
    const float* r0 = Whh0 + (size_t)(wv*512 + hs*16 + row)*512 + qh*8;
    const float* r1 = Whh1 + (size_t)(wv*512 + hs*16 + row)*512 + qh*8;
#pragma unroll
    for (int kt = 0; kt < 16; ++kt) {
      float xs[8];
      float4 v0 = *(const float4*)(r0 + kt*32), v1 = *(const float4*)(r0 + kt*32 + 4);
      xs[0]=v0.x; xs[1]=v0.y; xs[2]=v0.z; xs[3]=v0.w;
      xs[4]=v1.x; xs[5]=v1.y; xs[6]=v1.z; xs[7]=v1.w;
      split_pack8(xs, w0h[kt], w0l[kt]);
      v0 = *(const float4*)(r1 + kt*32); v1 = *(const float4*)(r1 + kt*32 + 4);
      xs[0]=v0.x; xs[1]=v0.y; xs[2]=v0.z; xs[3]=v0.w;
      xs[4]=v1.x; xs[5]=v1.y; xs[6]=v1.z; xs[7]=v1.w;
      split_pack8(xs, w1h[kt], w1l[kt]);
    }
  }

  const int b_l = tid >> 4, uu = tid & 15;
  const int bglob = bg*16 + b_l;
  const size_t bgoff = (size_t)bg*8192;
  const int oct_p = hs*2 + (uu >> 3);
  const size_t widx = (size_t)b_l*512 + (size_t)(uu & 1)*256
                    + ((size_t)(oct_p ^ b_l) << 2) + (size_t)((uu & 7) >> 1);
  const int len_b = lens[bglob];
  const int lenA  = lens[bg*16 + row];       // A-frag row mask (per lane)
  float c0_reg = cb0[(size_t)bglob*512 + hs*16 + uu];
  float c1_reg = cb1[(size_t)bglob*512 + hs*16 + uu];
  float h0_reg, h1_reg;
  {
    size_t ib = (size_t)(s0 & 1)*65536 + bgoff + (size_t)b_l*512
              + ((size_t)(oct_p ^ b_l) << 2) + (size_t)((uu & 7) >> 1);
    uint32_t hiw = mb0[ib], low = mb0[ib + 256];
    int sh = (uu & 1) * 16;
    h0_reg = f16val((uint16_t)(hiw >> sh)) + f16val((uint16_t)(low >> sh)) * LOINV;
    int s1i = (s0 >= 1) ? (s0 - 1) : 0;
    size_t ib1 = (size_t)(s1i & 1)*65536 + bgoff + (size_t)b_l*512
               + ((size_t)(oct_p ^ b_l) << 2) + (size_t)((uu & 7) >> 1);
    hiw = mb1[ib1]; low = mb1[ib1 + 256];
    h1_reg = f16val((uint16_t)(hiw >> sh)) + f16val((uint16_t)(low >> sh)) * LOINV;
  }
  float b1g[4];
#pragma unroll
  for (int g = 0; g < 4; ++g)
    b1g[g] = bih1[g*512 + hs*16 + uu] + bhh1[g*512 + hs*16 + uu];
  const size_t yfl = (size_t)(hs >> 1)*4096 + (size_t)bg*512 + (size_t)(uu & 1)*256
                   + (size_t)((((hs & 1) << 1) | (uu >> 3)))*64 + (size_t)b_l*4
                   + (size_t)((uu & 7) >> 1);

  asm volatile("s_waitcnt vmcnt(0)" ::: "memory");   // Wih1 LDS staging done
  __syncthreads();

  for (int it = 0; it < nt; ++it) {
    const int t = s0 + it;
    const bool aL0 = (t < 256);
    const bool aL1 = (t > 0);

    // Xg0 prefetch (fp16, overlaps flag wait)
    uint16_t x0w[4] = {0,0,0,0};
    if (aL0) {
      const uint16_t* xgp = xg + ((size_t)it*128 + bglob)*2048 + hs*16 + uu;
      x0w[0] = xgp[0]; x0w[1] = xgp[512]; x0w[2] = xgp[1024]; x0w[3] = xgp[1536];
    }

    // concurrent polls: wave0 -> flg0 >= t, wave1 -> flg1 >= t-1 (L2-local)
    if (it > 0) {
      if (wv == 0) {
        const uint32_t* fp = flg0 + bg*32 + (lane & 31);
        while (1) {
          uint32_t f = __hip_atomic_load(fp, __ATOMIC_RELAXED, __HIP_MEMORY_SCOPE_AGENT);
          if (__all((int)(f >= (uint32_t)t))) break;
          __builtin_amdgcn_s_sleep(1);
        }
      } else if (wv == 1) {
        const uint32_t* fp = flg1 + bg*32 + (lane & 31);
        while (1) {
          uint32_t f = __hip_atomic_load(fp, __ATOMIC_RELAXED, __HIP_MEMORY_SCOPE_AGENT);
          if (__all((int)(f >= (uint32_t)(t - 1)))) break;
          __builtin_amdgcn_s_sleep(1);
        }
      }
    }
    __builtin_amdgcn_s_barrier();                      // (1) producers ready
    __builtin_amdgcn_sched_barrier(0);

    // stage BOTH tiles (independent buffers, one barrier)
    {
      const uint64_t* sp0 = (const uint64_t*)(mb0 + (size_t)(t & 1)*65536 + bgoff);
      const uint64_t* sp1 = (const uint64_t*)(mb1 + (size_t)((t - 1) & 1)*65536 + bgoff);
      uint64_t v0[16], v1[16];
#pragma unroll
      for (int e = 0; e < 16; ++e)
        v0[e] = __hip_atomic_load(sp0 + tid + e*256, __ATOMIC_RELAXED, __HIP_MEMORY_SCOPE_AGENT);
      if (aL1) {
#pragma unroll
        for (int e = 0; e < 16; ++e)
          v1[e] = __hip_atomic_load(sp1 + tid + e*256, __ATOMIC_RELAXED, __HIP_MEMORY_SCOPE_AGENT);
      }
#pragma unroll
      for (int e = 0; e < 16; ++e)
        tA64[tid + e*256] = v0[e];
      if (aL1) {
#pragma unroll
        for (int e = 0; e < 16; ++e)
          tB64[tid + e*256] = v1[e];
      }
    }
    asm volatile("s_waitcnt lgkmcnt(0)" ::: "memory");
    __builtin_amdgcn_s_barrier();                      // (2) both tiles staged
    __builtin_amdgcn_sched_barrier(0);

    // one MFMA block: G0+G1 on tileA, then G2 on tileB (no barrier between)
    f32x4 A0 = (f32x4){0,0,0,0}, A1 = (f32x4){0,0,0,0}, A2 = (f32x4){0,0,0,0};
    f32x4 B0 = (f32x4){0,0,0,0}, B1 = (f32x4){0,0,0,0}, B2 = (f32x4){0,0,0,0};
    {
      const uint8_t* hrp = tileA + (size_t)row*2048;
      const uint8_t* wbase = wih + (size_t)wv*16384;
      const bool cY = aL1 && ((t - 1) < lenA);
      const uint4 z4 = make_uint4(0,0,0,0);
#pragma unroll
      for (int kt = 0; kt < 16; ++kt) {
        int oct = kt*4 + qh;
        const uint8_t* pA = hrp + (((oct ^ row)) << 4);
        uint4 ah = *(const uint4*)pA, al = *(const uint4*)(pA + 1024);
        A0 = mfma16(ah, w0h[kt], A0);
        A1 = mfma16(al, w0h[kt], A1);
        A2 = mfma16(ah, w0l[kt], A2);
        uint4 yh = cY ? ah : z4, yl = cY ? al : z4;
        uint4 bh = *(const uint4*)(wbase + (size_t)kt*1024 + lane*16);
        B0 = mfma16(yh, bh, B0);
        B1 = mfma16(yl, bh, B1);
      }
    }
    if (aL1) {
      const uint8_t* hrp = tileB + (size_t)row*2048;
#pragma unroll
      for (int kt = 0; kt < 16; ++kt) {
        int oct = kt*4 + qh;
        const uint8_t* pA = hrp + (((oct ^ row)) << 4);
        uint4 ah = *(const uint4*)pA, al = *(const uint4*)(pA + 1024);
        B0 = mfma16(ah, w1h[kt], B0);
        B1 = mfma16(al, w1h[kt], B1);
        B2 = mfma16(ah, w1l[kt], B2);
      }
    }

    // gate exchange (dedicated region; own-wave data only)
    {
      int col = lane & 15, rb = (lane >> 4) << 2;
      if (aL0) {
#pragma unroll
        for (int r = 0; r < 4; ++r)
          g0ex[(size_t)(wv*16 + rb + r)*16 + col] = A0[r] + (A1[r] + A2[r])*LOINV;
      }
      if (aL1) {
#pragma unroll
        for (int r = 0; r < 4; ++r)
          g1ex[(size_t)(wv*16 + rb + r)*16 + col] = B0[r] + (B1[r] + B2[r])*LOINV;
      }
    }
    asm volatile("s_waitcnt lgkmcnt(0)" ::: "memory");
    __builtin_amdgcn_s_barrier();                      // (3) gates exchanged
    __builtin_amdgcn_sched_barrier(0);

    uint32_t p1w = 0; bool m1 = false;
    if (aL0) {
      float gi = g0ex[(size_t)(0*16 + b_l)*16 + uu] + f16val(x0w[0]);
      float gf = g0ex[(size_t)(1*16 + b_l)*16 + uu] + f16val(x0w[1]);
      float gg = g0ex[(size_t)(2*16 + b_l)*16 + uu] + f16val(x0w[2]);
      float go = g0ex[(size_t)(3*16 + b_l)*16 + uu] + f16val(x0w[3]);
      float cn = fsigm(gf)*c0_reg + fsigm(gi)*ftanh(gg);
      float hn = fsigm(go)*ftanh(cn);
      bool m = (t < len_b);
      c0_reg = m ? cn : c0_reg;
      h0_reg = m ? hn : h0_reg;
      uint32_t p = split_ph2(h0_reg);
      uint32_t pp = __shfl_xor(p, 1);
      __hip_atomic_store(mb0 + (size_t)((t + 1) & 1)*65536 + bgoff + widx,
                         plane_word(p, pp, uu & 1), __ATOMIC_RELAXED, __HIP_MEMORY_SCOPE_AGENT);
    }
    if (aL1) {
      float gi = g1ex[(size_t)(0*16 + b_l)*16 + uu] + b1g[0];
      float gf = g1ex[(size_t)(1*16 + b_l)*16 + uu] + b1g[1];
      float gg = g1ex[(size_t)(2*16 + b_l)*16 + uu] + b1g[2];
      float go = g1ex[(size_t)(3*16 + b_l)*16 + uu] + b1g[3];
      float cn = fsigm(gf)*c1_reg + fsigm(gi)*ftanh(gg);
      float hn = fsigm(go)*ftanh(cn);
      m1 = ((t - 1) < len_b);
      c1_reg = m1 ? cn : c1_reg;
      h1_reg = m1 ? hn : h1_reg;
      uint32_t p = split_ph2(h1_reg);
      uint32_t pp = __shfl_xor(p, 1);
      p1w = plane_word(p, pp, uu & 1);
      __hip_atomic_store(mb1 + (size_t)(t & 1)*65536 + bgoff + widx,
                         p1w, __ATOMIC_RELAXED, __HIP_MEMORY_SCOPE_AGENT);
    }
    asm volatile("s_waitcnt vmcnt(0)" ::: "memory");
    __builtin_amdgcn_s_barrier();                      // (4) publishes in L2
    __builtin_amdgcn_sched_barrier(0);
    if (tid == 0) {
      if (aL0) __hip_atomic_store(flg0 + bg*32 + hs, (uint32_t)(t + 1),
                                  __ATOMIC_RELAXED, __HIP_MEMORY_SCOPE_AGENT);
      if (aL1) __hip_atomic_store(flg1 + bg*32 + hs, (uint32_t)t,
                                  __ATOMIC_RELAXED, __HIP_MEMORY_SCOPE_AGENT);
    }
    if (aL1) y1buf[(size_t)(t - 1)*65536 + yfl] = m1 ? p1w : 0u;
  }
  cb0[(size_t)bglob*512 + hs*16 + uu] = c0_reg;
  cb1[(size_t)bglob*512 + hs*16 + uu] = c1_reg;
}

// ---------------------------------------------------------------------------
// small epilogue kernels
// ---------------------------------------------------------------------------
__global__ __launch_bounds__(256) void k_pack2(const float* __restrict__ a,
    const float* __restrict__ b, uint32_t* __restrict__ out)
{
  int i = blockIdx.x*256 + threadIdx.x;
  int bb = i >> 10, k = i & 1023;
  float x = (k < 512) ? a[(size_t)bb*512 + k] : b[(size_t)bb*512 + k - 512];
  out[i] = split_ph2(x);
}

__global__ __launch_bounds__(256) void k_tanh_split(const float* __restrict__ c,
    uint32_t* __restrict__ hp)
{ int i = blockIdx.x*256 + threadIdx.x; hp[i] = split_ph2(tanhf(c[i])); }

__global__ __launch_bounds__(256) void k_dec_cell(const float* __restrict__ g,
    const float* __restrict__ cdec, float* __restrict__ hout, float* __restrict__ dh)
{
  int i = blockIdx.x*256 + threadIdx.x;     // 65536
  int b = i >> 9, u = i & 511;
  const float* gb = g + (size_t)b*2048;
  float c = sigm(gb[512 + u])*cdec[i] + sigm(gb[u])*tanhf(gb[1024 + u]);
  float h = sigm(gb[1536 + u])*tanhf(c);
  hout[i] = h; dh[i] = h;
}

// scores -> masked softmax -> context; y1 is in fl layout
__global__ __launch_bounds__(256) void k_attn(const uint32_t* __restrict__ y1,
    const float* __restrict__ h, const int* __restrict__ lens,
    float* __restrict__ ctx, float* __restrict__ dctx)
{
  __shared__ float hsh[512];
  __shared__ float sc[256];
  __shared__ float red[8];
  const int b = blockIdx.x, tid = threadIdx.x, lane = tid & 63, wv = tid >> 6;
  hsh[tid]       = h[(size_t)b*512 + tid];
  hsh[tid + 256] = h[(size_t)b*512 + tid + 256];
  const int len = lens[b];
  __syncthreads();

  const size_t lanebase = (size_t)(lane >> 2)*4096 + (size_t)(b >> 4)*512
                        + (size_t)(lane & 3)*64 + (size_t)(b & 15)*4;
  for (int it = 0; it < 64; ++it) {
    int s = wv*64 + it;
    const uint32_t* yb = y1 + (size_t)s*65536 + lanebase;
    uint4 hw = *(const uint4*)yb;
    uint4 lw = *(const uint4*)(yb + 256);
    int k0 = lane*8;
    uint32_t hws[4] = {hw.x,hw.y,hw.z,hw.w}, lws[4] = {lw.x,lw.y,lw.z,lw.w};
    float d = 0.f;
#pragma unroll
    for (int w = 0; w < 4; ++w) {
      d += (f16val((uint16_t)hws[w]) + f16val((uint16_t)lws[w])*LOINV) * hsh[k0 + 2*w]
         + (f16val((uint16_t)(hws[w]>>16)) + f16val((uint16_t)(lws[w]>>16))*LOINV) * hsh[k0 + 2*w + 1];
    }
    for (int off = 32; off; off >>= 1) d += __shfl_xor(d, off);
    if (lane == 0) sc[s] = d;
  }
  __syncthreads();

  float v = (tid < len) ? sc[tid] : -INFINITY;
  float mx = v;
  for (int off = 32; off; off >>= 1) mx = fmaxf(mx, __shfl_xor(mx, off));
  if (lane == 0) red[wv] = mx;
  __syncthreads();
  mx = fmaxf(fmaxf(red[0], red[1]), fmaxf(red[2], red[3]));
  float e = (tid < len) ? expf(v - mx) : 0.f;
  float ssum = e;
  for (int off = 32; off; off >>= 1) ssum += __shfl_xor(ssum, off);
  if (lane == 0) red[4 + wv] = ssum;
  __syncthreads();
  float tot = red[4] + red[5] + red[6] + red[7];
  __syncthreads();
  sc[tid] = e / tot;
  __syncthreads();

  const int u0 = tid, u1 = tid + 256;
  const size_t bu0 = (size_t)(u0 >> 5)*4096 + (size_t)(b >> 4)*512
                   + (size_t)((u0 >> 3) & 3)*64 + (size_t)(b & 15)*4 + (size_t)((u0 & 7) >> 1);
  const size_t bu1 = (size_t)(u1 >> 5)*4096 + (size_t)(b >> 4)*512
                   + (size_t)((u1 >> 3) & 3)*64 + (size_t)(b & 15)*4 + (size_t)((u1 & 7) >> 1);
  const int sh = (tid & 1) * 16;
  float acc0 = 0.f, acc1 = 0.f;
  for (int s = 0; s < 256; ++s) {
    float w = sc[s];
    const uint32_t* yb = y1 + (size_t)s*65536;
    uint32_t hi0 = yb[bu0], lo0 = yb[bu0 + 256];
    uint32_t hi1 = yb[bu1], lo1 = yb[bu1 + 256];
    acc0 += w*(f16val((uint16_t)(hi0 >> sh)) + f16val((uint16_t)(lo0 >> sh))*LOINV);
    acc1 += w*(f16val((uint16_t)(hi1 >> sh)) + f16val((uint16_t)(lo1 >> sh))*LOINV);
  }
  ctx [(size_t)b*512 + tid]       = acc0;  ctx [(size_t)b*512 + tid + 256] = acc1;
  dctx[(size_t)b*512 + tid]       = acc0;  dctx[(size_t)b*512 + tid + 256] = acc1;
}

__global__ __launch_bounds__(256) void k_argmax(const float* __restrict__ logits,
    float* __restrict__ out)
{
  __shared__ float bv[256];
  __shared__ int   bi[256];
  const int b = blockIdx.x, tid = threadIdx.x;
  const float* L = logits + (size_t)b*32000;
  float best = -INFINITY; int idx = 0;
  for (int i = tid; i < 32000; i += 256) {
    float v = L[i];
    if (v > best) { best = v; idx = i; }
  }
  bv[tid] = best; bi[tid] = idx;
  __syncthreads();
  for (int sft = 128; sft; sft >>= 1) {
    if (tid < sft) {
      if (bv[tid+sft] > bv[tid] || (bv[tid+sft] == bv[tid] && bi[tid+sft] < bi[tid])) {
        bv[tid] = bv[tid+sft]; bi[tid] = bi[tid+sft];
      }
    }
    __syncthreads();
  }
  if (tid == 0) out[b] = (float)bi[0];
}

// ---------------------------------------------------------------------------
// launcher
// ---------------------------------------------------------------------------
extern "C" void kernel_launch(void* const* d_in, const int* in_sizes, int n_in,
                              void* d_out, int out_size, void* d_ws, size_t ws_size,
                              hipStream_t stream)
{
  (void)in_sizes; (void)n_in; (void)out_size; (void)ws_size;
  const int*   src_tokens = (const int*)  d_in[0];
  const int*   src_lens   = (const int*)  d_in[1];
  const int*   trg_tokens = (const int*)  d_in[2];
  const float* src_emb    = (const float*)d_in[3];
  const float* trg_emb    = (const float*)d_in[4];
  const float* Wih0 = (const float*)d_in[5];
  const float* Whh0 = (const float*)d_in[6];
  const float* bih0 = (const float*)d_in[7];
  const float* bhh0 = (const float*)d_in[8];
  const float* Wih1 = (const float*)d_in[9];
  const float* Whh1 = (const float*)d_in[10];
  const float* bih1 = (const float*)d_in[11];
  const float* bhh1 = (const float*)d_in[12];
  const float* dWih = (const float*)d_in[13];
  const float* dWhh = (const float*)d_in[14];
  const float* dbih = (const float*)d_in[15];
  const float* dbhh = (const float*)d_in[16];
  const float* Winit= (const float*)d_in[17];
  const float* binit= (const float*)d_in[18];
  const float* Whid = (const float*)d_in[19];
  const float* bhid = (const float*)d_in[20];
  const float* Wout = (const float*)d_in[21];
  const float* bout = (const float*)d_in[22];

  uint8_t* ws = (uint8_t*)d_ws;
  constexpr size_t MBs = 1ull << 20;
  constexpr size_t OFF_AP    = 0;                         // 64MB fl src embeds
  constexpr size_t OFF_Y1    = 64*MBs;                    // 64MB fl y1
  constexpr size_t OFF_XG    = 128*MBs;                   // 32MB fp16 Xg
  constexpr size_t OFF_MB    = 192*MBs;                   // 1MB: mb0 | mb1
  constexpr size_t OFF_CB0   = OFF_MB    + 1*MBs;
  constexpr size_t OFF_CB1   = OFF_CB0   + 256*1024;
  constexpr size_t OFF_FLG   = OFF_CB1   + 256*1024;      // flg0 | claim(+1024) | flg1(+2048)
  constexpr size_t OFF_PK    = OFF_FLG   + 4096;
  constexpr size_t OFF_CDEC  = OFF_PK    + 512*1024;
  constexpr size_t OFF_HDECP = OFF_CDEC  + 256*1024;
  constexpr size_t OFF_EMBP  = OFF_HDECP + 256*1024;
  constexpr size_t OFF_G     = OFF_EMBP  + 256*1024;
  constexpr size_t OFF_HDEC2 = OFF_G     + 1*MBs;
  constexpr size_t OFF_CTX   = OFF_HDEC2 + 256*1024;
  constexpr size_t OFF_AVEC  = OFF_CTX   + 256*1024;
  constexpr size_t OFF_AVECP = OFF_AVEC  + 256*1024;
  constexpr size_t OFF_LOG   = OFF_AVECP + 256*1024;      // 16MB logits; Wp0/Wp1 overlay

  uint32_t* Ap    = (uint32_t*)(ws + OFF_AP);
  uint32_t* Y1    = (uint32_t*)(ws + OFF_Y1);
  uint16_t* Xg    = (uint16_t*)(ws + OFF_XG);
  uint32_t* mb0   = (uint32_t*)(ws + OFF_MB);
  uint32_t* mb1   = (uint32_t*)(ws + OFF_MB + 512*1024);
  float*    cb0   = (float*)   (ws + OFF_CB0);
  float*    cb1   = (float*)   (ws + OFF_CB1);
  uint32_t* flg0  = (uint32_t*)(ws + OFF_FLG);
  uint32_t* xclm  = (uint32_t*)(ws + OFF_FLG + 1024);
  uint32_t* flg1  = (uint32_t*)(ws + OFF_FLG + 2048);
  uint32_t* pk    = (uint32_t*)(ws + OFF_PK);
  float*    cdec  = (float*)   (ws + OFF_CDEC);
  uint32_t* hdecp = (uint32_t*)(ws + OFF_HDECP);
  uint32_t* embp  = (uint32_t*)(ws + OFF_EMBP);
  float*    g     = (float*)   (ws + OFF_G);
  float*    hdec2 = (float*)   (ws + OFF_HDEC2);
  float*    ctx   = (float*)   (ws + OFF_CTX);
  float*    avec  = (float*)   (ws + OFF_AVEC);
  uint32_t* avecp = (uint32_t*)(ws + OFF_AVECP);
  float*    logit = (float*)   (ws + OFF_LOG);
  uint32_t* Wp0   = (uint32_t*)(ws + OFF_LOG);            // overlays logits
  uint32_t* Wp1   = (uint32_t*)(ws + OFF_LOG + 4*MBs);
  float*    dout  = (float*)   d_out;

  // ---- pre-split encoder input weights to fl ----
  k_packW<<<4096, 256, 0, stream>>>(Wih0, Wp0);
  k_packW<<<4096, 256, 0, stream>>>(Wih1, Wp1);

  // ---- encoder: fused two-layer pipeline (XCD-local rings) ----
  hipMemsetAsync(mb0,  0, 1024*1024, stream);   // both mailboxes -> h(0)=0
  hipMemsetAsync(flg0, 0, 4096, stream);        // flags + claim counters
  hipMemsetAsync(cb0,  0, 65536*4, stream);
  hipMemsetAsync(cb1,  0, 65536*4, stream);
  k_embed_src_fl<<<2048, 256, 0, stream>>>(src_tokens, src_emb, Ap);
  for (int c = 0; c < 4; ++c) {
    int s0 = c * 64;
    k_gemm_fl<<<dim3(16, 64), 256, 0, stream>>>(Ap + (size_t)s0*65536,
        Wp0, bih0, bhh0, (float*)Xg, 2048, 0, 2);
    k_lstm2<<<256, 256, 0, stream>>>(Whh0, Whh1, bih1, bhh1, Xg, src_lens,
        mb0, mb1, cb0, cb1, Y1, flg0, flg1, xclm, Wp1, s0, (c == 3) ? 65 : 64);
  }

  // ---- decoder init ----
  k_pack2<<<512, 256, 0, stream>>>(cb0, cb1, pk);
  k_gemm<<<dim3(4, 1), 256, 0, stream>>>(pk, 1024, Winit, 1024, binit, nullptr,
      cdec, 512, 1024, 0);
  k_tanh_split<<<256, 256, 0, stream>>>(cdec, hdecp);

  // ---- decoder LSTM step ----
  k_embed_trg<<<256, 256, 0, stream>>>(trg_tokens, trg_emb, embp);
  k_gemm<<<dim3(16, 1), 256, 0, stream>>>(embp, 512, dWih, 1024, dbih, dbhh,
      g, 2048, 512, 0);
  k_gemm<<<dim3(16, 1), 256, 0, stream>>>(hdecp, 512, dWhh, 512, nullptr, nullptr,
      g, 2048, 512, 1);
  k_dec_cell<<<256, 256, 0, stream>>>(g, cdec, hdec2, dout + 65536);

  // ---- attention (fl reads) ----
  k_attn<<<128, 256, 0, stream>>>(Y1, hdec2, src_lens, ctx, dout);

  // ---- output projection + argmax (Wout read directly as f32) ----
  k_pack2<<<512, 256, 0, stream>>>(hdec2, ctx, pk);
  k_gemm<<<dim3(4, 1), 256, 0, stream>>>(pk, 1024, Whid, 1024, bhid, nullptr,
      avec, 512, 1024, 0);
  k_pack1<<<256, 256, 0, stream>>>(avec, avecp);
  k_gemm<<<dim3(250, 1), 256, 0, stream>>>(avecp, 512, Wout, 512, bout, nullptr,
      logit, 32000, 512, 0);
  k_argmax<<<128, 256, 0, stream>>>(logit, dout + 131072);
}